// Round 7
// baseline (319.612 us; speedup 1.0000x reference)
//
#include <hip/hip_runtime.h>

// Fused 6-layer MLP, v8: W1 in VGPRs (bf16-packed), x streamed global->regs
// as wave-contiguous 256B bursts. Zero main-loop LDS traffic.
// Block 256 = 4 independent waves; wave owns 16 consecutive rows (50KB stream).
// Lane owns k = lane + 64t (t=0..11; lanes<16 also own k=768+lane).
// Per row: 13 coalesced dword loads, 144 FMA + 72 unpack-shl, 12 j x 4 DPP
// row_ror adds (VALU reduction to 16-lane groups), 3 ds_write_b128 by group
// leaders. Every 16 rows: v2-style epilogue (4 lanes/row, shfl_xor(1,2),
// tiny layers redundant, vectorized stores).

__device__ __forceinline__ float ftanh(float v) {
    float e = __expf(2.0f * v);
    return 1.0f - 2.0f / (e + 1.0f);
}

__device__ __forceinline__ uint32_t bfpack(float lo, float hi) {
    uint32_t ul = __float_as_uint(lo);
    uint32_t uh = __float_as_uint(hi);
    ul += 0x7fffu + ((ul >> 16) & 1u);   // RTN to bf16
    uh += 0x7fffu + ((uh >> 16) & 1u);
    return (ul >> 16) | (uh & 0xffff0000u);
}

template <int CTRL>
__device__ __forceinline__ float dpp_add(float v) {
    int m = __builtin_amdgcn_update_dpp(0, __float_as_int(v), CTRL, 0xF, 0xF, false);
    return v + __int_as_float(m);
}

// full sum within each 16-lane row: ror 8,4,2,1 (pure VALU, no LDS)
__device__ __forceinline__ float rowsum16(float v) {
    v = dpp_add<0x128>(v);   // row_ror:8
    v = dpp_add<0x124>(v);   // row_ror:4
    v = dpp_add<0x122>(v);   // row_ror:2
    v = dpp_add<0x121>(v);   // row_ror:1
    return v;
}

__global__ __launch_bounds__(256, 4)
void mlp_fused8(const float* __restrict__ x,
                const float* __restrict__ W1, const float* __restrict__ b1,
                const float* __restrict__ W2, const float* __restrict__ b2,
                const float* __restrict__ W3, const float* __restrict__ b3,
                const float* __restrict__ W4, const float* __restrict__ b4,
                const float* __restrict__ W5, const float* __restrict__ b5,
                const float* __restrict__ W6, const float* __restrict__ b6,
                float* __restrict__ out)
{
    __shared__ float h1lds[4][16][4][12];   // [wave][row][kgroup][j] = 12 KB

    const int tid  = threadIdx.x;
    const int wave = tid >> 6;
    const int lane = tid & 63;
    const int row_base = (blockIdx.x * 4 + wave) << 4;   // 16 rows per wave

    // ---- W1 -> registers, bf16-packed: lane owns k = lane + 64t ----
    uint32_t w1pk[78];
#pragma unroll
    for (int t = 0; t < 12; ++t) {
        const float4* wr = (const float4*)(W1 + (size_t)(t * 64 + lane) * 12);
        float4 q0 = wr[0], q1 = wr[1], q2 = wr[2];
        w1pk[t * 6 + 0] = bfpack(q0.x, q0.y);
        w1pk[t * 6 + 1] = bfpack(q0.z, q0.w);
        w1pk[t * 6 + 2] = bfpack(q1.x, q1.y);
        w1pk[t * 6 + 3] = bfpack(q1.z, q1.w);
        w1pk[t * 6 + 4] = bfpack(q2.x, q2.y);
        w1pk[t * 6 + 5] = bfpack(q2.z, q2.w);
    }
    if (lane < 16) {                        // tail k = 768 + lane
        const float4* wr = (const float4*)(W1 + (size_t)(768 + lane) * 12);
        float4 q0 = wr[0], q1 = wr[1], q2 = wr[2];
        w1pk[72] = bfpack(q0.x, q0.y);
        w1pk[73] = bfpack(q0.z, q0.w);
        w1pk[74] = bfpack(q1.x, q1.y);
        w1pk[75] = bfpack(q1.z, q1.w);
        w1pk[76] = bfpack(q2.x, q2.y);
        w1pk[77] = bfpack(q2.z, q2.w);
    }

    const float* xr = x + (size_t)row_base * 784;

    auto loadx = [&](float (&buf)[13], int rr) {
        const float* p = xr + rr * 784;
#pragma unroll
        for (int t = 0; t < 12; ++t) buf[t] = p[t * 64 + lane];
        if (lane < 16) buf[12] = p[768 + lane];
    };

    auto compute = [&](const float (&buf)[13], int rr) {
        float acc[12];
#pragma unroll
        for (int j = 0; j < 12; ++j) acc[j] = 0.f;
#pragma unroll
        for (int t = 0; t < 12; ++t) {
            float xx = buf[t];
#pragma unroll
            for (int c = 0; c < 6; ++c) {
                uint32_t u = w1pk[t * 6 + c];
                acc[2 * c]     += xx * __uint_as_float(u << 16);
                acc[2 * c + 1] += xx * __uint_as_float(u);   // junk low bits ~ bf16 ulp
            }
        }
        if (lane < 16) {                    // tail k
            float xx = buf[12];
#pragma unroll
            for (int c = 0; c < 6; ++c) {
                uint32_t u = w1pk[72 + c];
                acc[2 * c]     += xx * __uint_as_float(u << 16);
                acc[2 * c + 1] += xx * __uint_as_float(u);
            }
        }
#pragma unroll
        for (int j = 0; j < 12; ++j) acc[j] = rowsum16(acc[j]);
        if ((lane & 15) == 0) {
            float4* p = (float4*)&h1lds[wave][rr][lane >> 4][0];
            p[0] = make_float4(acc[0], acc[1], acc[2],  acc[3]);
            p[1] = make_float4(acc[4], acc[5], acc[6],  acc[7]);
            p[2] = make_float4(acc[8], acc[9], acc[10], acc[11]);
        }
    };

    // ---- main loop: 16 rows, double-buffered x ----
    float xA[13], xB[13];
    loadx(xA, 0);
    for (int rr = 0; rr < 16; rr += 2) {
        loadx(xB, rr + 1);
        compute(xA, rr);
        if (rr + 2 < 16) loadx(xA, rr + 2);
        compute(xB, rr + 1);
    }

    // ---- epilogue: 4 lanes per row ----
    const int r   = lane >> 2;
    const int sub = lane & 3;
    const int row = row_base + r;

    const float4* pp = (const float4*)&h1lds[wave][r][sub][0];
    float4 a0 = pp[0], a1 = pp[1], a2 = pp[2];

    float h1[12];
#define REDJ(dst, v0)                                                      \
    { float v = (v0); v += __shfl_xor(v, 1); v += __shfl_xor(v, 2); dst = v; }
    REDJ(h1[0],  a0.x) REDJ(h1[1],  a0.y) REDJ(h1[2],  a0.z) REDJ(h1[3],  a0.w)
    REDJ(h1[4],  a1.x) REDJ(h1[5],  a1.y) REDJ(h1[6],  a1.z) REDJ(h1[7],  a1.w)
    REDJ(h1[8],  a2.x) REDJ(h1[9],  a2.y) REDJ(h1[10], a2.z) REDJ(h1[11], a2.w)
#undef REDJ
#pragma unroll
    for (int j = 0; j < 12; ++j) h1[j] = ftanh(h1[j] + b1[j]);

    float h2[10];
#pragma unroll
    for (int m = 0; m < 10; ++m) {
        float s = b2[m];
#pragma unroll
        for (int j = 0; j < 12; ++j) s += h1[j] * W2[j * 10 + m];
        h2[m] = ftanh(s);
    }
    float h3[8];
#pragma unroll
    for (int m = 0; m < 8; ++m) {
        float s = b3[m];
#pragma unroll
        for (int j = 0; j < 10; ++j) s += h2[j] * W3[j * 8 + m];
        h3[m] = ftanh(s);
    }
    float h4[6];
#pragma unroll
    for (int m = 0; m < 6; ++m) {
        float s = b4[m];
#pragma unroll
        for (int j = 0; j < 8; ++j) s += h3[j] * W4[j * 6 + m];
        h4[m] = ftanh(s);
    }
    float h5[4];
#pragma unroll
    for (int m = 0; m < 4; ++m) {
        float s = b5[m];
#pragma unroll
        for (int j = 0; j < 6; ++j) s += h4[j] * W5[j * 4 + m];
        h5[m] = ftanh(s);
    }
    float o[10];
#pragma unroll
    for (int m = 0; m < 10; ++m) {
        float s = b6[m];
#pragma unroll
        for (int j = 0; j < 4; ++j) s += h5[j] * W6[j * 10 + m];
        o[m] = s;   // logits
    }

    // ---- vectorized stores, round-robined over sub ----
    const size_t H1 = 655360, H2 = 1441792, H3 = 2097152, H4 = 2621440, H5 = 3014656;
    float2* po  = (float2*)(out +      (size_t)row * 10);
    float4* ph1 = (float4*)(out + H1 + (size_t)row * 12);
    float2* ph2 = (float2*)(out + H2 + (size_t)row * 10);
    float4* ph3 = (float4*)(out + H3 + (size_t)row * 8);
    float2* ph4 = (float2*)(out + H4 + (size_t)row * 6);
    float4* ph5 = (float4*)(out + H5 + (size_t)row * 4);

    if (sub == 0) {
        po[0]  = make_float2(o[0], o[1]);
        po[4]  = make_float2(o[8], o[9]);
        ph2[0] = make_float2(h2[0], h2[1]);
        ph2[4] = make_float2(h2[8], h2[9]);
        ph4[1] = make_float2(h4[2], h4[3]);
    } else if (sub == 1) {
        po[1]  = make_float2(o[2], o[3]);
        ph1[0] = make_float4(h1[0], h1[1], h1[2], h1[3]);
        ph2[1] = make_float2(h2[2], h2[3]);
        ph3[0] = make_float4(h3[0], h3[1], h3[2], h3[3]);
        ph4[2] = make_float2(h4[4], h4[5]);
    } else if (sub == 2) {
        po[2]  = make_float2(o[4], o[5]);
        ph1[1] = make_float4(h1[4], h1[5], h1[6], h1[7]);
        ph2[2] = make_float2(h2[4], h2[5]);
        ph3[1] = make_float4(h3[4], h3[5], h3[6], h3[7]);
        ph5[0] = make_float4(h5[0], h5[1], h5[2], h5[3]);
    } else {
        po[3]  = make_float2(o[6], o[7]);
        ph1[2] = make_float4(h1[8], h1[9], h1[10], h1[11]);
        ph2[3] = make_float2(h2[6], h2[7]);
        ph4[0] = make_float2(h4[0], h4[1]);
    }
}

extern "C" void kernel_launch(void* const* d_in, const int* in_sizes, int n_in,
                              void* d_out, int out_size, void* d_ws, size_t ws_size,
                              hipStream_t stream) {
    (void)in_sizes; (void)n_in; (void)d_ws; (void)ws_size; (void)out_size;
    mlp_fused8<<<1024, 256, 0, stream>>>(
        (const float*)d_in[0],
        (const float*)d_in[1],  (const float*)d_in[2],
        (const float*)d_in[3],  (const float*)d_in[4],
        (const float*)d_in[5],  (const float*)d_in[6],
        (const float*)d_in[7],  (const float*)d_in[8],
        (const float*)d_in[9],  (const float*)d_in[10],
        (const float*)d_in[11], (const float*)d_in[12],
        (float*)d_out);
}

// Round 8
// 264.855 us; speedup vs baseline: 1.2067x; 1.2067x over previous
//
#include <hip/hip_runtime.h>

// Fused 6-layer MLP, v9: v8's dataflow (W1 bf16-packed in VGPRs, x streamed
// global->reg as 256B coalesced bursts, DPP 16-lane reduce, zero main-loop
// LDS) with the scratch bug fixed: NO lambdas, flat code, compile-time
// array indices only, no double-buffer, branchless zero-W tail.
// Block 256 = 4 independent waves; wave owns 16 consecutive rows.
// Lane owns k = lane + 64t (t=0..11); tail k=768+lane for lanes<16 via
// zeroed W regs on lanes>=16 (branchless).

__device__ __forceinline__ float ftanh(float v) {
    float e = __expf(2.0f * v);
    return 1.0f - 2.0f / (e + 1.0f);
}

__device__ __forceinline__ uint32_t bfpack(float lo, float hi) {
    uint32_t ul = __float_as_uint(lo);
    uint32_t uh = __float_as_uint(hi);
    ul += 0x7fffu + ((ul >> 16) & 1u);   // RTN to bf16
    uh += 0x7fffu + ((uh >> 16) & 1u);
    return (ul >> 16) | (uh & 0xffff0000u);
}

template <int CTRL>
__device__ __forceinline__ float dpp_add(float v) {
    int m = __builtin_amdgcn_update_dpp(0, __float_as_int(v), CTRL, 0xF, 0xF, false);
    return v + __int_as_float(m);
}

// full sum within each 16-lane group: row_ror 8,4,2,1 (pure VALU)
__device__ __forceinline__ float rowsum16(float v) {
    v = dpp_add<0x128>(v);
    v = dpp_add<0x124>(v);
    v = dpp_add<0x122>(v);
    v = dpp_add<0x121>(v);
    return v;
}

__global__ __launch_bounds__(256, 4)
void mlp_fused9(const float* __restrict__ x,
                const float* __restrict__ W1, const float* __restrict__ b1,
                const float* __restrict__ W2, const float* __restrict__ b2,
                const float* __restrict__ W3, const float* __restrict__ b3,
                const float* __restrict__ W4, const float* __restrict__ b4,
                const float* __restrict__ W5, const float* __restrict__ b5,
                const float* __restrict__ W6, const float* __restrict__ b6,
                float* __restrict__ out)
{
    __shared__ float h1lds[4][16][4][12];   // [wave][row][kgroup][j] = 12 KB

    const int tid  = threadIdx.x;
    const int wave = tid >> 6;
    const int lane = tid & 63;
    const int row_base = (blockIdx.x * 4 + wave) << 4;   // 16 rows per wave

    // ---- W1 -> registers, bf16-packed: lane owns k = lane + 64t ----
    uint32_t w1pk[78];
#pragma unroll
    for (int t = 0; t < 12; ++t) {
        const float4* wr = (const float4*)(W1 + (size_t)(t * 64 + lane) * 12);
        float4 q0 = wr[0], q1 = wr[1], q2 = wr[2];
        w1pk[t * 6 + 0] = bfpack(q0.x, q0.y);
        w1pk[t * 6 + 1] = bfpack(q0.z, q0.w);
        w1pk[t * 6 + 2] = bfpack(q1.x, q1.y);
        w1pk[t * 6 + 3] = bfpack(q1.z, q1.w);
        w1pk[t * 6 + 4] = bfpack(q2.x, q2.y);
        w1pk[t * 6 + 5] = bfpack(q2.z, q2.w);
    }
    {   // tail k = 768 + (lane&15); lanes >= 16 get zeroed W (branchless FMA)
        const uint32_t msk = (lane < 16) ? 0xffffffffu : 0u;
        const float4* wr = (const float4*)(W1 + (size_t)(768 + (lane & 15)) * 12);
        float4 q0 = wr[0], q1 = wr[1], q2 = wr[2];
        w1pk[72] = bfpack(q0.x, q0.y) & msk;
        w1pk[73] = bfpack(q0.z, q0.w) & msk;
        w1pk[74] = bfpack(q1.x, q1.y) & msk;
        w1pk[75] = bfpack(q1.z, q1.w) & msk;
        w1pk[76] = bfpack(q2.x, q2.y) & msk;
        w1pk[77] = bfpack(q2.z, q2.w) & msk;
    }

    const float* xr = x + (size_t)row_base * 784;

    // ---- main loop: 16 rows, flat (no lambdas, no dbuf) ----
    for (int rr = 0; rr < 16; ++rr) {
        const float* p = xr + rr * 784;

        float xb[13];
#pragma unroll
        for (int t = 0; t < 12; ++t) xb[t] = p[t * 64 + lane];
        xb[12] = p[768 + (lane & 15)];       // valid addr for all lanes

        float acc[12];
#pragma unroll
        for (int j = 0; j < 12; ++j) acc[j] = 0.f;

#pragma unroll
        for (int t = 0; t < 13; ++t) {
            float xx = xb[t];
#pragma unroll
            for (int c = 0; c < 6; ++c) {
                uint32_t u = w1pk[t * 6 + c];
                acc[2 * c]     += xx * __uint_as_float(u << 16);
                acc[2 * c + 1] += xx * __uint_as_float(u);   // junk low bits ~ bf16 ulp
            }
        }

#pragma unroll
        for (int j = 0; j < 12; ++j) acc[j] = rowsum16(acc[j]);

        if ((lane & 15) == 0) {
            float4* q = (float4*)&h1lds[wave][rr][lane >> 4][0];
            q[0] = make_float4(acc[0], acc[1], acc[2],  acc[3]);
            q[1] = make_float4(acc[4], acc[5], acc[6],  acc[7]);
            q[2] = make_float4(acc[8], acc[9], acc[10], acc[11]);
        }
    }

    __syncthreads();

    // ---- epilogue: 4 lanes per row (identical to v8, which passed) ----
    const int r   = lane >> 2;
    const int sub = lane & 3;
    const int row = row_base + r;

    const float4* pp = (const float4*)&h1lds[wave][r][sub][0];
    float4 a0 = pp[0], a1 = pp[1], a2 = pp[2];

    float h1[12];
#define REDJ(dst, v0)                                                      \
    { float v = (v0); v += __shfl_xor(v, 1); v += __shfl_xor(v, 2); dst = v; }
    REDJ(h1[0],  a0.x) REDJ(h1[1],  a0.y) REDJ(h1[2],  a0.z) REDJ(h1[3],  a0.w)
    REDJ(h1[4],  a1.x) REDJ(h1[5],  a1.y) REDJ(h1[6],  a1.z) REDJ(h1[7],  a1.w)
    REDJ(h1[8],  a2.x) REDJ(h1[9],  a2.y) REDJ(h1[10], a2.z) REDJ(h1[11], a2.w)
#undef REDJ
#pragma unroll
    for (int j = 0; j < 12; ++j) h1[j] = ftanh(h1[j] + b1[j]);

    float h2[10];
#pragma unroll
    for (int m = 0; m < 10; ++m) {
        float s = b2[m];
#pragma unroll
        for (int j = 0; j < 12; ++j) s += h1[j] * W2[j * 10 + m];
        h2[m] = ftanh(s);
    }
    float h3[8];
#pragma unroll
    for (int m = 0; m < 8; ++m) {
        float s = b3[m];
#pragma unroll
        for (int j = 0; j < 10; ++j) s += h2[j] * W3[j * 8 + m];
        h3[m] = ftanh(s);
    }
    float h4[6];
#pragma unroll
    for (int m = 0; m < 6; ++m) {
        float s = b4[m];
#pragma unroll
        for (int j = 0; j < 8; ++j) s += h3[j] * W4[j * 6 + m];
        h4[m] = ftanh(s);
    }
    float h5[4];
#pragma unroll
    for (int m = 0; m < 4; ++m) {
        float s = b5[m];
#pragma unroll
        for (int j = 0; j < 6; ++j) s += h4[j] * W5[j * 4 + m];
        h5[m] = ftanh(s);
    }
    float o[10];
#pragma unroll
    for (int m = 0; m < 10; ++m) {
        float s = b6[m];
#pragma unroll
        for (int j = 0; j < 4; ++j) s += h5[j] * W6[j * 10 + m];
        o[m] = s;   // logits
    }

    // ---- vectorized stores, round-robined over sub ----
    const size_t H1 = 655360, H2 = 1441792, H3 = 2097152, H4 = 2621440, H5 = 3014656;
    float2* po  = (float2*)(out +      (size_t)row * 10);
    float4* ph1 = (float4*)(out + H1 + (size_t)row * 12);
    float2* ph2 = (float2*)(out + H2 + (size_t)row * 10);
    float4* ph3 = (float4*)(out + H3 + (size_t)row * 8);
    float2* ph4 = (float2*)(out + H4 + (size_t)row * 6);
    float4* ph5 = (float4*)(out + H5 + (size_t)row * 4);

    if (sub == 0) {
        po[0]  = make_float2(o[0], o[1]);
        po[4]  = make_float2(o[8], o[9]);
        ph2[0] = make_float2(h2[0], h2[1]);
        ph2[4] = make_float2(h2[8], h2[9]);
        ph4[1] = make_float2(h4[2], h4[3]);
    } else if (sub == 1) {
        po[1]  = make_float2(o[2], o[3]);
        ph1[0] = make_float4(h1[0], h1[1], h1[2], h1[3]);
        ph2[1] = make_float2(h2[2], h2[3]);
        ph3[0] = make_float4(h3[0], h3[1], h3[2], h3[3]);
        ph4[2] = make_float2(h4[4], h4[5]);
    } else if (sub == 2) {
        po[2]  = make_float2(o[4], o[5]);
        ph1[1] = make_float4(h1[4], h1[5], h1[6], h1[7]);
        ph2[2] = make_float2(h2[4], h2[5]);
        ph3[1] = make_float4(h3[4], h3[5], h3[6], h3[7]);
        ph5[0] = make_float4(h5[0], h5[1], h5[2], h5[3]);
    } else {
        po[3]  = make_float2(o[6], o[7]);
        ph1[2] = make_float4(h1[8], h1[9], h1[10], h1[11]);
        ph2[3] = make_float2(h2[6], h2[7]);
        ph4[0] = make_float2(h4[0], h4[1]);
    }
}

extern "C" void kernel_launch(void* const* d_in, const int* in_sizes, int n_in,
                              void* d_out, int out_size, void* d_ws, size_t ws_size,
                              hipStream_t stream) {
    (void)in_sizes; (void)n_in; (void)d_ws; (void)ws_size; (void)out_size;
    mlp_fused9<<<1024, 256, 0, stream>>>(
        (const float*)d_in[0],
        (const float*)d_in[1],  (const float*)d_in[2],
        (const float*)d_in[3],  (const float*)d_in[4],
        (const float*)d_in[5],  (const float*)d_in[6],
        (const float*)d_in[7],  (const float*)d_in[8],
        (const float*)d_in[9],  (const float*)d_in[10],
        (const float*)d_in[11], (const float*)d_in[12],
        (float*)d_out);
}

// Round 9
// 46.259 us; speedup vs baseline: 6.9093x; 5.7255x over previous
//
#include <hip/hip_runtime.h>

// Fused 6-layer MLP, v10: v7 shell + v_dot2_f32_bf16 inner loop.
// W1 in LDS as bf16 pairs packed along k: u32[pair p][j] = {lo=w[2p][j], hi=w[2p+1][j]}.
// x converted pairwise with v_cvt_pk_bf16_f32. Per 16-k iter per thread:
// 6 ds_read_b128 (was 12) + 24 v_dot2 + 2 cvt_pk (was 48 FMA).
// Block = 512 threads = 128 rows x 4 k-sublanes. Grid = 512 blocks.
// LDS = 18.8 KB. Depth-2 x prefetch. Epilogue identical to v7.

__device__ __forceinline__ float ftanh(float v) {
    float e = __expf(2.0f * v);
    return 1.0f - 2.0f / (e + 1.0f);
}

__device__ __forceinline__ uint32_t cvtpk(float lo, float hi) {
    uint32_t d;
    asm("v_cvt_pk_bf16_f32 %0, %1, %2" : "=v"(d) : "v"(lo), "v"(hi));
    return d;
}

__device__ __forceinline__ float dot2(uint32_t a, uint32_t b, float c) {
    float d;
    asm("v_dot2_f32_bf16 %0, %1, %2, %3" : "=v"(d) : "v"(a), "v"(b), "v"(c));
    return d;
}

__global__ __launch_bounds__(512, 6)
void mlp_fused10(const float* __restrict__ x,
                 const float* __restrict__ W1, const float* __restrict__ b1,
                 const float* __restrict__ W2, const float* __restrict__ b2,
                 const float* __restrict__ W3, const float* __restrict__ b3,
                 const float* __restrict__ W4, const float* __restrict__ b4,
                 const float* __restrict__ W5, const float* __restrict__ b5,
                 const float* __restrict__ W6, const float* __restrict__ b6,
                 float* __restrict__ out)
{
    __shared__ uint32_t ldsW[4704];        // 392 k-pairs x 12 j = 18816 B

    const int tid = threadIdx.x;

    // ---- stage W1 -> LDS as packed bf16 k-pairs (RNE via cvt_pk) ----
    for (int t = tid; t < 4704; t += 512) {
        int p = t / 12, j = t - p * 12;
        ldsW[t] = cvtpk(W1[p * 24 + j], W1[p * 24 + 12 + j]);
    }
    __syncthreads();

    const int lane = tid & 63;
    const int wave = tid >> 6;              // 0..7
    const int r    = lane >> 2;             // row within 16-row wave group
    const int sub  = lane & 3;              // k-quarter within 64B line
    const int row  = (blockIdx.x << 7) + (wave << 4) + r;

    // ---- layer 1: acc over k, 4 lanes per row, depth-2 prefetch ----
    float acc[12];
#pragma unroll
    for (int j = 0; j < 12; ++j) acc[j] = 0.f;

    const float4* xrow = (const float4*)(x + (size_t)row * 784);

    float4 f0 = xrow[sub];
    float4 f1 = xrow[4 + sub];

#pragma unroll 7
    for (int i = 0; i < 49; ++i) {
        int pf = (i + 2 < 49) ? (i + 2) : 47;        // branchless clamp
        float4 f2 = xrow[pf * 4 + sub];

        // pairs p0 = i*8 + sub*2 and p0+1; 12 u32 each
        const uint4* wb = (const uint4*)(ldsW + i * 96 + sub * 24);
        uint4 A0 = wb[0], A1 = wb[1], A2 = wb[2];    // pair p0:  j 0..11
        uint4 B0 = wb[3], B1 = wb[4], B2 = wb[5];    // pair p0+1

        uint32_t xp0 = cvtpk(f0.x, f0.y);            // k even/odd of pair p0
        uint32_t xp1 = cvtpk(f0.z, f0.w);            // pair p0+1

        acc[0]  = dot2(xp0, A0.x, acc[0]);
        acc[1]  = dot2(xp0, A0.y, acc[1]);
        acc[2]  = dot2(xp0, A0.z, acc[2]);
        acc[3]  = dot2(xp0, A0.w, acc[3]);
        acc[4]  = dot2(xp0, A1.x, acc[4]);
        acc[5]  = dot2(xp0, A1.y, acc[5]);
        acc[6]  = dot2(xp0, A1.z, acc[6]);
        acc[7]  = dot2(xp0, A1.w, acc[7]);
        acc[8]  = dot2(xp0, A2.x, acc[8]);
        acc[9]  = dot2(xp0, A2.y, acc[9]);
        acc[10] = dot2(xp0, A2.z, acc[10]);
        acc[11] = dot2(xp0, A2.w, acc[11]);

        acc[0]  = dot2(xp1, B0.x, acc[0]);
        acc[1]  = dot2(xp1, B0.y, acc[1]);
        acc[2]  = dot2(xp1, B0.z, acc[2]);
        acc[3]  = dot2(xp1, B0.w, acc[3]);
        acc[4]  = dot2(xp1, B1.x, acc[4]);
        acc[5]  = dot2(xp1, B1.y, acc[5]);
        acc[6]  = dot2(xp1, B1.z, acc[6]);
        acc[7]  = dot2(xp1, B1.w, acc[7]);
        acc[8]  = dot2(xp1, B2.x, acc[8]);
        acc[9]  = dot2(xp1, B2.y, acc[9]);
        acc[10] = dot2(xp1, B2.z, acc[10]);
        acc[11] = dot2(xp1, B2.w, acc[11]);

        f0 = f1;
        f1 = f2;
    }

    // ---- reduce 4 sub-partials (within 4-lane group) + bias + tanh ----
    float h1[12];
#pragma unroll
    for (int j = 0; j < 12; ++j) {
        float z = acc[j];
        z += __shfl_xor(z, 1);
        z += __shfl_xor(z, 2);
        h1[j] = ftanh(z + b1[j]);
    }

    // ---- tiny layers 2..6 (redundant on all 4 sub-lanes; uniform W via s_load) ----
    float h2[10];
#pragma unroll
    for (int m = 0; m < 10; ++m) {
        float s = b2[m];
#pragma unroll
        for (int j = 0; j < 12; ++j) s += h1[j] * W2[j * 10 + m];
        h2[m] = ftanh(s);
    }

    float h3[8];
#pragma unroll
    for (int m = 0; m < 8; ++m) {
        float s = b3[m];
#pragma unroll
        for (int j = 0; j < 10; ++j) s += h2[j] * W3[j * 8 + m];
        h3[m] = ftanh(s);
    }

    float h4[6];
#pragma unroll
    for (int m = 0; m < 6; ++m) {
        float s = b4[m];
#pragma unroll
        for (int j = 0; j < 8; ++j) s += h3[j] * W4[j * 6 + m];
        h4[m] = ftanh(s);
    }

    float h5[4];
#pragma unroll
    for (int m = 0; m < 4; ++m) {
        float s = b5[m];
#pragma unroll
        for (int j = 0; j < 6; ++j) s += h4[j] * W5[j * 4 + m];
        h5[m] = ftanh(s);
    }

    float o[10];
#pragma unroll
    for (int m = 0; m < 10; ++m) {
        float s = b6[m];
#pragma unroll
        for (int j = 0; j < 4; ++j) s += h5[j] * W6[j * 10 + m];
        o[m] = s;   // logits
    }

    // ---- vectorized stores, round-robined over sub (compile-time reg indices) ----
    const size_t H1 = 655360, H2 = 1441792, H3 = 2097152, H4 = 2621440, H5 = 3014656;
    float2* po  = (float2*)(out +      (size_t)row * 10);
    float4* ph1 = (float4*)(out + H1 + (size_t)row * 12);
    float2* ph2 = (float2*)(out + H2 + (size_t)row * 10);
    float4* ph3 = (float4*)(out + H3 + (size_t)row * 8);
    float2* ph4 = (float2*)(out + H4 + (size_t)row * 6);
    float4* ph5 = (float4*)(out + H5 + (size_t)row * 4);

    if (sub == 0) {
        po[0]  = make_float2(o[0], o[1]);
        po[4]  = make_float2(o[8], o[9]);
        ph2[0] = make_float2(h2[0], h2[1]);
        ph2[4] = make_float2(h2[8], h2[9]);
        ph4[1] = make_float2(h4[2], h4[3]);
    } else if (sub == 1) {
        po[1]  = make_float2(o[2], o[3]);
        ph1[0] = make_float4(h1[0], h1[1], h1[2], h1[3]);
        ph2[1] = make_float2(h2[2], h2[3]);
        ph3[0] = make_float4(h3[0], h3[1], h3[2], h3[3]);
        ph4[2] = make_float2(h4[4], h4[5]);
    } else if (sub == 2) {
        po[2]  = make_float2(o[4], o[5]);
        ph1[1] = make_float4(h1[4], h1[5], h1[6], h1[7]);
        ph2[2] = make_float2(h2[4], h2[5]);
        ph3[1] = make_float4(h3[4], h3[5], h3[6], h3[7]);
        ph5[0] = make_float4(h5[0], h5[1], h5[2], h5[3]);
    } else {
        po[3]  = make_float2(o[6], o[7]);
        ph1[2] = make_float4(h1[8], h1[9], h1[10], h1[11]);
        ph2[3] = make_float2(h2[6], h2[7]);
        ph4[0] = make_float2(h4[0], h4[1]);
    }
}

extern "C" void kernel_launch(void* const* d_in, const int* in_sizes, int n_in,
                              void* d_out, int out_size, void* d_ws, size_t ws_size,
                              hipStream_t stream) {
    (void)in_sizes; (void)n_in; (void)d_ws; (void)ws_size; (void)out_size;
    mlp_fused10<<<512, 512, 0, stream>>>(
        (const float*)d_in[0],
        (const float*)d_in[1],  (const float*)d_in[2],
        (const float*)d_in[3],  (const float*)d_in[4],
        (const float*)d_in[5],  (const float*)d_in[6],
        (const float*)d_in[7],  (const float*)d_in[8],
        (const float*)d_in[9],  (const float*)d_in[10],
        (const float*)d_in[11], (const float*)d_in[12],
        (float*)d_out);
}